// Round 5
// baseline (38.820 us; speedup 1.0000x reference)
//
#include <hip/hip_runtime.h>
#include <hip/hip_bf16.h>

#define NNODES 4096
#define NF 64
#define NH 8
#define ND 8
#define HD 64   // NH*ND

// Load element i from a buffer that is either f32 or bf16 (uniform flag).
__device__ __forceinline__ float ldv(const void* p, int i, bool f32) {
    return f32 ? ((const float*)p)[i]
               : __bfloat162float(((const __hip_bfloat16*)p)[i]);
}

// Load 8 consecutive elements (idx 8-aligned) as f32.
__device__ __forceinline__ void ld8(const void* base, int idx, bool f32, float* o) {
    if (f32) {
        const float4* p = (const float4*)((const float*)base + idx);
        float4 a = p[0], b = p[1];
        o[0]=a.x; o[1]=a.y; o[2]=a.z; o[3]=a.w;
        o[4]=b.x; o[5]=b.y; o[6]=b.z; o[7]=b.w;
    } else {
        uint4 u = *(const uint4*)((const unsigned short*)base + idx);
        unsigned int ws[4] = {u.x, u.y, u.z, u.w};
        #pragma unroll
        for (int q = 0; q < 4; ++q) {
            o[2*q]   = __uint_as_float(ws[q] << 16);          // low bf16
            o[2*q+1] = __uint_as_float(ws[q] & 0xffff0000u);  // high bf16
        }
    }
}

// A[0][0] == 1.0 always (self loop): u32 0x3F800000 iff f32.
__device__ __forceinline__ bool a_is_f32(const void* A) {
    return *(const unsigned int*)A == 0x3F800000u;
}

// ---------------------------------------------------------------------------
// Kernel A: logits only.  U[f,h] = sum_d W[f,h*8+d]*att_self[h,d] (V likewise);
// a_self = X@U, a_neigh = X@V.  256 blocks x 16 rows.
// ---------------------------------------------------------------------------
__global__ __launch_bounds__(256) void gat_logits(
    const void* __restrict__ X, const void* __restrict__ W,
    const void* __restrict__ att_s, const void* __restrict__ att_n,
    const void* __restrict__ A,
    float* __restrict__ a_self, float* __restrict__ a_neigh)
{
    const bool f32 = a_is_f32(A);
    __shared__ float UV[NF * 17];   // [f][c6], c6<8 = U(h), c6>=8 = V(h-8); pad 17
    __shared__ float Xl[16 * 65];   // 16 rows, pad 65
    const int t = threadIdx.x;

    #pragma unroll
    for (int rep = 0; rep < 4; ++rep) {
        int idx = t + rep * 256;          // 0..1023
        int f = idx >> 4, c6 = idx & 15;
        int h = c6 & 7;
        float wv[8];
        ld8(W, f * HD + h * ND, f32, wv);
        const void* att = (c6 < 8) ? att_s : att_n;
        float s = 0.f;
        #pragma unroll
        for (int d = 0; d < 8; ++d)
            s = fmaf(wv[d], ldv(att, h * 8 + d, f32), s);
        UV[f * 17 + c6] = s;
    }
    if (t < 128) {
        int row = t >> 3, col = (t & 7) * 8;
        float xv[8];
        ld8(X, (blockIdx.x * 16 + row) * NF + col, f32, xv);
        #pragma unroll
        for (int k = 0; k < 8; ++k) Xl[row * 65 + col + k] = xv[k];
    }
    __syncthreads();

    const int r = t >> 4, c6 = t & 15;
    float s = 0.f;
    #pragma unroll
    for (int f = 0; f < NF; ++f)
        s = fmaf(Xl[r * 65 + f], UV[f * 17 + c6], s);
    const int n = blockIdx.x * 16 + r;
    if (c6 < 8) a_self[n * NH + c6]       = s;
    else        a_neigh[n * NH + (c6-8)]  = s;
}

// ---------------------------------------------------------------------------
// Kernel B: per-row masked softmax + X-aggregation + deferred W multiply.
// One block (256 thr, 4 waves) per row.
// ---------------------------------------------------------------------------
__global__ __launch_bounds__(256) void gat_aggr(
    const void* __restrict__ A,
    const void* __restrict__ X,
    const void* __restrict__ W,
    const void* __restrict__ bias,
    const float* __restrict__ a_self_g,
    const float* __restrict__ a_neigh,
    float* __restrict__ out)
{
    const int i = blockIdx.x;
    const int t = threadIdx.x;
    const bool f32 = a_is_f32(A);
    const int wave = t >> 6, lane = t & 63;

    __shared__ float Wlf[NF * HD];      // 16 KB f32 W
    __shared__ float shbuf[2048];       // 8 KB: elist (phase 0-2) then red[4][512]
    __shared__ float agg[NH * 65];      // padded cross-wave-reduced aggX
    __shared__ float dsh[4][NH];
    __shared__ float denT[NH];
    __shared__ float fin[4][HD];
    __shared__ int wtot[4];
    unsigned short* elist = (unsigned short*)shbuf;
    float* red = shbuf;

    // ---- stage W -> LDS f32 (independent; overlaps A-row latency) ----
    {
        float wv[16];
        ld8(W, t * 16,     f32, wv);
        ld8(W, t * 16 + 8, f32, wv + 8);
        #pragma unroll
        for (int k = 0; k < 16; ++k) Wlf[t * 16 + k] = wv[k];
    }

    // ---- Phase 0: read 16 consecutive A entries -> bits ----
    unsigned int bits = 0;
    if (f32) {
        const uint4* ap = (const uint4*)((const float*)A + (size_t)i * NNODES + t * 16);
        #pragma unroll
        for (int q = 0; q < 4; ++q) {
            uint4 p = ap[q];
            if (p.x) bits |= 1u << (4*q+0);
            if (p.y) bits |= 1u << (4*q+1);
            if (p.z) bits |= 1u << (4*q+2);
            if (p.w) bits |= 1u << (4*q+3);
        }
    } else {
        const uint4* ap = (const uint4*)((const unsigned short*)A + (size_t)i * NNODES + t * 16);
        uint4 p0 = ap[0], p1 = ap[1];
        unsigned int w0[4] = {p0.x, p0.y, p0.z, p0.w};
        unsigned int w1[4] = {p1.x, p1.y, p1.z, p1.w};
        #pragma unroll
        for (int q = 0; q < 4; ++q) {
            if (w0[q] & 0x0000ffffu) bits |= 1u << (2*q);
            if (w0[q] & 0xffff0000u) bits |= 1u << (2*q+1);
            if (w1[q] & 0x0000ffffu) bits |= 1u << (8+2*q);
            if (w1[q] & 0xffff0000u) bits |= 1u << (8+2*q+1);
        }
    }

    // ---- Phase 1: deterministic compaction into elist (ascending j) ----
    int cnt = __popc(bits);
    int incl = cnt;
    #pragma unroll
    for (int off = 1; off < 64; off <<= 1) {
        int nn = __shfl_up(incl, off, 64);
        if (lane >= off) incl += nn;
    }
    if (lane == 63) wtot[wave] = incl;
    __syncthreads();
    int base = 0;
    #pragma unroll
    for (int w = 0; w < 4; ++w) if (w < wave) base += wtot[w];
    const int nE = wtot[0] + wtot[1] + wtot[2] + wtot[3];
    int off0 = base + (incl - cnt);
    unsigned int mb = bits;
    while (mb) {
        int b = __ffs(mb) - 1; mb &= mb - 1;
        elist[off0++] = (unsigned short)(t * 16 + b);
    }
    __syncthreads();

    // ---- Phase 2: aggregate X directly. lane = h*8+fs ----
    const int h = lane >> 3, fs = lane & 7;
    const float ash = a_self_g[i * NH + h];
    float acc[8] = {0,0,0,0,0,0,0,0};
    float den = 0.f;

    const int chunk = (nE + 3) >> 2;
    int e = wave * chunk;
    const int eEnd = min(nE, e + chunk);

    for (; e + 2 <= eEnd; e += 2) {
        int j0 = elist[e], j1 = elist[e + 1];
        float x0[8], x1[8];
        ld8(X, j0 * NF + fs * 8, f32, x0);
        ld8(X, j1 * NF + fs * 8, f32, x1);
        float an0 = a_neigh[j0 * NH + h];
        float an1 = a_neigh[j1 * NH + h];
        float s0 = ash + an0; s0 = (s0 >= 0.f) ? s0 : 0.2f * s0; float w0 = __expf(s0);
        float s1 = ash + an1; s1 = (s1 >= 0.f) ? s1 : 0.2f * s1; float w1 = __expf(s1);
        #pragma unroll
        for (int k = 0; k < 8; ++k) {
            acc[k] = fmaf(w0, x0[k], acc[k]);
            acc[k] = fmaf(w1, x1[k], acc[k]);
        }
        den += w0 + w1;
    }
    if (e < eEnd) {
        int j = elist[e];
        float xv[8];
        ld8(X, j * NF + fs * 8, f32, xv);
        float s = ash + a_neigh[j * NH + h];
        s = (s >= 0.f) ? s : 0.2f * s;
        float wt = __expf(s);
        #pragma unroll
        for (int k = 0; k < 8; ++k) acc[k] = fmaf(wt, xv[k], acc[k]);
        den += wt;
    }
    __syncthreads();   // all elist reads done before red overwrites it

    // per-wave partials: red[wave*512 + h*64 + fs*8 + k]  (lane*8 == h*64+fs*8)
    #pragma unroll
    for (int k = 0; k < 8; ++k) red[wave * 512 + lane * 8 + k] = acc[k];
    if (fs == 0) dsh[wave][h] = den;
    __syncthreads();

    // ---- cross-wave reduce into padded agg ----
    #pragma unroll
    for (int rr = 0; rr < 2; ++rr) {
        int idx = t * 2 + rr;                 // 0..511
        int hh = idx >> 6, ff = idx & 63;
        float v = red[idx] + red[512 + idx] + red[1024 + idx] + red[1536 + idx];
        agg[hh * 65 + ff] = v;
    }
    if (t < NH) denT[t] = dsh[0][t] + dsh[1][t] + dsh[2][t] + dsh[3][t];
    __syncthreads();

    // ---- deferred W multiply: wave covers f in [wave*16, wave*16+16) ----
    {
        const int c = lane, hh = c >> 3;
        float p = 0.f;
        #pragma unroll
        for (int f0 = 0; f0 < 16; ++f0) {
            int f = wave * 16 + f0;
            p = fmaf(agg[hh * 65 + f], Wlf[f * HD + c], p);
        }
        fin[wave][c] = p;
    }
    __syncthreads();

    if (t < HD) {
        float tot = fin[0][t] + fin[1][t] + fin[2][t] + fin[3][t];
        float v = tot / denT[t >> 3] + ldv(bias, t, f32);
        out[(size_t)i * HD + t] = fmaxf(v, 0.f);   // f32 output
    }
}

// ---------------------------------------------------------------------------
extern "C" void kernel_launch(void* const* d_in, const int* in_sizes, int n_in,
                              void* d_out, int out_size, void* d_ws, size_t ws_size,
                              hipStream_t stream) {
    const void* X         = d_in[0];
    const void* A         = d_in[1];
    const void* W         = d_in[2];
    const void* att_self  = d_in[3];
    const void* att_neigh = d_in[4];
    const void* bias      = d_in[5];
    float* out = (float*)d_out;

    float* a_self  = (float*)d_ws;                  // 4096*8 f32
    float* a_neigh = a_self + NNODES * NH;          // 4096*8 f32

    gat_logits<<<NNODES / 16, 256, 0, stream>>>(X, W, att_self, att_neigh, A,
                                                a_self, a_neigh);
    gat_aggr<<<NNODES, 256, 0, stream>>>(A, X, W, bias, a_self, a_neigh, out);
}